// Round 12
// baseline (345.985 us; speedup 1.0000x reference)
//
#include <hip/hip_runtime.h>

#define HID 10
#define STEPS 512

typedef __attribute__((ext_vector_type(2))) float v2f;

// ds_swizzle BitMode: src = ((lane & and) | or_) ^ xor ; offset = (xor<<10)|(or<<5)|and
template<int PAT>
static __device__ __forceinline__ float dsw(float v) {
    return __int_as_float(__builtin_amdgcn_ds_swizzle(__float_as_int(v), PAT));
}

// DPP row_ror:J within 16-lane rows (VALU pipe). Self-calibrated via irot probe,
// so the rotation direction convention is irrelevant. Even J preserves lane parity.
template<int J>
static __device__ __forceinline__ float frot(float v) {
    return __int_as_float(__builtin_amdgcn_update_dpp(
        0, __float_as_int(v), 0x120 + J, 0xF, 0xF, true));
}
template<int J>
static __device__ __forceinline__ int irot(int v) {
    return __builtin_amdgcn_update_dpp(0, v, 0x120 + J, 0xF, 0xF, true);
}

// Lane-parallel fused GRU decoder, EIGHT lanes per batch:
//   16-lane row = 2 batches interleaved by parity p = sub&1; slot s = sub>>1.
//   Lane owns features f0 = s (always valid) and f1 = 8+s (valid s<2).
//   batch = blockIdx*8 + (lane>>4)*2 + p.  Grid 1024 = 1 wave/SIMD.
// v12 rationale: every prior variant paid a full LDS roundtrip on the recurrence
// chain (v7: 723 cyc/8batches = 434 issue + 290 stall; stagger/dual-stream/pair-
// packing all null or worse). This layout makes the gather VALU-only:
//   h[0..7]: 7 parity-preserving DPP row_ror (even amounts, ~4cy, independent);
//   h[8],h[9]: 2 ds_swizzle (and=0x11 keeps row+parity), issued at loop top,
//   consumed LAST in the dot chains -> latency hidden under DPP+pk work.
// Dots: 5 pk-families x 10 terms = 50 pk_fma per 8 batches (vs ~110 MACs in v7),
// even/odd split (depth 5, 10 independent chains). Weight k-order is permuted
// per lane by the gather -> tables built from the same irot probe (R2/R3-proven).
__attribute__((amdgpu_waves_per_eu(1, 1)))
__global__ __launch_bounds__(64) void gru_decoder_kernel(
    const float* __restrict__ hidden, const float* __restrict__ w_ih,
    const float* __restrict__ w_hh, const float* __restrict__ b_ih,
    const float* __restrict__ b_hh, const float* __restrict__ l1_w,
    const float* __restrict__ l1_b, const float* __restrict__ l2_w,
    const float* __restrict__ l2_b, float* __restrict__ out)
{
    __shared__ float sWx[640];   // l2_w @ l1_w (64x10)
    __shared__ float sbx[64];    // l2_w @ l1_b + l2_b
    __shared__ float sWgi[300];  // w_ih @ Wx (30x10)
    __shared__ float sbgi[30];   // b_ih + w_ih @ bx
    __shared__ float sWhh[300];  // w_hh copy (t=0 peel + weight build)

    const int lane = threadIdx.x;
    const int sub  = lane & 15;
    const int row  = lane >> 4;
    const int p    = sub & 1;
    const int s    = sub >> 1;
    const int b    = blockIdx.x * 8 + row * 2 + p;
    const int f0   = s;                 // 0..7, always valid
    const bool ok1 = (s < 2);
    const int fi1  = ok1 ? (8 + s) : 8; // clamped for safe reads

    // ---- preamble: fused weights (fp32, cooperative) ----
    for (int e = lane; e < 640; e += 64) {
        int i = e / 10, j = e - i * 10;
        float acc = 0.f;
        #pragma unroll
        for (int k = 0; k < 10; ++k) acc += l2_w[i * 10 + k] * l1_w[k * 10 + j];
        sWx[e] = acc;
    }
    {
        float acc = l2_b[lane];
        #pragma unroll
        for (int k = 0; k < 10; ++k) acc += l2_w[lane * 10 + k] * l1_b[k];
        sbx[lane] = acc;
    }
    for (int e = lane; e < 300; e += 64) sWhh[e] = w_hh[e];
    __syncthreads();
    for (int e = lane; e < 300; e += 64) {
        int m = e / 10, j = e - m * 10;
        float acc = 0.f;
        for (int k = 0; k < 64; ++k) acc += w_ih[m * 64 + k] * sWx[k * 10 + j];
        sWgi[e] = acc;
    }
    if (lane < 30) {
        float acc = b_ih[lane];
        for (int k = 0; k < 64; ++k) acc += w_ih[lane * 64 + k] * sbx[k];
        sbgi[lane] = acc;
    }
    __syncthreads();

    const float LOG2E = 1.4426950408889634f;
    const float S2    = 2.f * LOG2E;

    // ---- self-calibrated gather source indices (even rotations, 16-ring) ----
    int idx[8];
    idx[0] = sub;
    idx[1] = irot<2>(sub);  idx[2] = irot<4>(sub);  idx[3] = irot<6>(sub);
    idx[4] = irot<8>(sub);  idx[5] = irot<10>(sub); idx[6] = irot<12>(sub);
    idx[7] = irot<14>(sub);

    // ---- per-lane weight tables, k-order = gather order (slots 8,9 = k=8,9) ----
    auto WR = [&](int ff, int k) { return -(sWgi[ff * 10 + k] + sWhh[ff * 10 + k]) * LOG2E; };
    auto WZ = [&](int ff, int k) { return -(sWgi[(10 + ff) * 10 + k] + sWhh[(10 + ff) * 10 + k]) * LOG2E; };
    auto WI = [&](int ff, int k) { return sWgi[(20 + ff) * 10 + k] * S2; };
    auto WH = [&](int ff, int k) { return sWhh[(20 + ff) * 10 + k] * S2; };

    v2f wrz0[10], wih0[10], wrz1[10], wih1[10], woo[10];
    #pragma unroll
    for (int j = 0; j < 10; ++j) {
        int k = (j < 8) ? (idx[j] >> 1) : j;   // slots 8,9 pair with h8g,h9g
        wrz0[j] = v2f{WR(f0, k), WZ(f0, k)};
        wih0[j] = v2f{WI(f0, k), WH(f0, k)};
        wrz1[j] = ok1 ? v2f{WR(fi1, k), WZ(fi1, k)} : v2f{0.f, 0.f};
        wih1[j] = ok1 ? v2f{WI(fi1, k), WH(fi1, k)} : v2f{0.f, 0.f};
        woo[j]  = v2f{l1_w[f0 * 10 + k], ok1 ? l1_w[fi1 * 10 + k] : 0.f};
    }
    const v2f Brz0 = {-(sbgi[f0] + b_hh[f0]) * LOG2E,
                      -(sbgi[10 + f0] + b_hh[10 + f0]) * LOG2E};
    const v2f Bih0 = {sbgi[20 + f0] * S2, b_hh[20 + f0] * S2};
    const v2f Brz1 = ok1 ? v2f{-(sbgi[fi1] + b_hh[fi1]) * LOG2E,
                               -(sbgi[10 + fi1] + b_hh[10 + fi1]) * LOG2E}
                         : v2f{0.f, 0.f};
    const v2f Bih1 = ok1 ? v2f{sbgi[20 + fi1] * S2, b_hh[20 + fi1] * S2} : v2f{0.f, 0.f};
    const v2f Boo  = {l1_b[f0], ok1 ? l1_b[fi1] : 0.f};
    // t=0 peel biases (gi = b_ih only)
    const float br0_0 = -(b_ih[f0] + b_hh[f0]) * LOG2E;
    const float bz0_0 = -(b_ih[10 + f0] + b_hh[10 + f0]) * LOG2E;
    const float bn0_0 = b_ih[20 + f0] * S2;
    const float br0_1 = -(b_ih[fi1] + b_hh[fi1]) * LOG2E;
    const float bz0_1 = -(b_ih[10 + fi1] + b_hh[10 + fi1]) * LOG2E;
    const float bn0_1 = b_ih[20 + fi1] * S2;

    // ---- initial h: lane owns h[f0] and (s<2) h[f1] of its batch ----
    float hx = hidden[(size_t)b * HID + f0];
    float hy = ok1 ? hidden[(size_t)b * HID + fi1] : 0.f;

    float* pb0 = out + (size_t)b * (STEPS * HID) + (size_t)(STEPS - 1) * HID + f0;
    float* pb1 = out + (size_t)b * (STEPS * HID) + (size_t)(STEPS - 1) * HID + fi1;

    // fused single-rcp tail (validated v6+): h' = (ez(en-1)+h(en+1))/((en+1)(1+ez))
    auto tail = [&](float arx, float azx, float aix, float ahx, float h) {
        float er = __builtin_amdgcn_exp2f(arx);
        float r  = __builtin_amdgcn_rcpf(1.f + er);
        float ez = __builtin_amdgcn_exp2f(azx);
        float y  = __builtin_fmaf(r, ahx, aix);
        float en = __builtin_amdgcn_exp2f(y);
        float pp = en * ez;
        float u  = pp + (h - ez);
        float num = __builtin_fmaf(h, en, u);
        float den = (pp + (en + ez)) + 1.f;
        return num * __builtin_amdgcn_rcpf(den);   // zero-weight lanes: stays 0
    };

    // ---- t = 0 peel: gi = b_ih only (x_0 = 0); raw w_hh dots from LDS ----
    {
        float g0 = hx,          g1 = frot<2>(hx),  g2 = frot<4>(hx),
              g3 = frot<6>(hx), g4 = frot<8>(hx),  g5 = frot<10>(hx),
              g6 = frot<12>(hx), g7 = frot<14>(hx);
        float h8g = dsw<0x0011>(hy), h9g = dsw<0x0051>(hy);
        float gv[8] = {g0, g1, g2, g3, g4, g5, g6, g7};
        float pr0 = 0.f, pz0 = 0.f, ph0 = 0.f, pr1 = 0.f, pz1 = 0.f, ph1 = 0.f;
        #pragma unroll
        for (int j = 0; j < 8; ++j) {
            int k = idx[j] >> 1;
            float hv = gv[j];
            pr0 += sWhh[f0 * 10 + k] * hv;
            pz0 += sWhh[(10 + f0) * 10 + k] * hv;
            ph0 += sWhh[(20 + f0) * 10 + k] * hv;
            pr1 += sWhh[fi1 * 10 + k] * hv;
            pz1 += sWhh[(10 + fi1) * 10 + k] * hv;
            ph1 += sWhh[(20 + fi1) * 10 + k] * hv;
        }
        pr0 += sWhh[f0 * 10 + 8] * h8g + sWhh[f0 * 10 + 9] * h9g;
        pz0 += sWhh[(10 + f0) * 10 + 8] * h8g + sWhh[(10 + f0) * 10 + 9] * h9g;
        ph0 += sWhh[(20 + f0) * 10 + 8] * h8g + sWhh[(20 + f0) * 10 + 9] * h9g;
        pr1 += sWhh[fi1 * 10 + 8] * h8g + sWhh[fi1 * 10 + 9] * h9g;
        pz1 += sWhh[(10 + fi1) * 10 + 8] * h8g + sWhh[(10 + fi1) * 10 + 9] * h9g;
        ph1 += sWhh[(20 + fi1) * 10 + 8] * h8g + sWhh[(20 + fi1) * 10 + 9] * h9g;
        hx = tail(br0_0 - pr0 * LOG2E, bz0_0 - pz0 * LOG2E,
                  bn0_0, ph0 * S2 + b_hh[20 + f0] * S2, hx);
        float ny = tail(br0_1 - pr1 * LOG2E, bz0_1 - pz1 * LOG2E,
                        bn0_1, ph1 * S2 + b_hh[20 + fi1] * S2, hy);
        hy = ok1 ? ny : 0.f;
    }

    #define HH(x) (v2f{(x), (x)})

    // ---- t = 1 .. 511 : VALU gather, 50 pk_fma, DS only for h8/h9 ----
    #pragma unroll 1
    for (int t = 1; t < STEPS; ++t) {
        float h8g = dsw<0x0011>(hy);     // issued first: latency hides under DPP+pk
        float h9g = dsw<0x0051>(hy);
        float g0 = hx,          g1 = frot<2>(hx),  g2 = frot<4>(hx),
              g3 = frot<6>(hx), g4 = frot<8>(hx),  g5 = frot<10>(hx),
              g6 = frot<12>(hx), g7 = frot<14>(hx);

        // even/odd chains; h8g/h9g terms last (slots 8,9)
        v2f aE0 = wrz0[0] * HH(g0) + Brz0;  v2f aO0 = wrz0[1] * HH(g1);
        v2f bE0 = wih0[0] * HH(g0) + Bih0;  v2f bO0 = wih0[1] * HH(g1);
        v2f aE1 = wrz1[0] * HH(g0) + Brz1;  v2f aO1 = wrz1[1] * HH(g1);
        v2f bE1 = wih1[0] * HH(g0) + Bih1;  v2f bO1 = wih1[1] * HH(g1);
        v2f oE  = woo[0]  * HH(g0) + Boo;   v2f oO  = woo[1]  * HH(g1);
        aE0 += wrz0[2] * HH(g2);  aO0 += wrz0[3] * HH(g3);
        bE0 += wih0[2] * HH(g2);  bO0 += wih0[3] * HH(g3);
        aE1 += wrz1[2] * HH(g2);  aO1 += wrz1[3] * HH(g3);
        bE1 += wih1[2] * HH(g2);  bO1 += wih1[3] * HH(g3);
        oE  += woo[2]  * HH(g2);  oO  += woo[3]  * HH(g3);
        aE0 += wrz0[4] * HH(g4);  aO0 += wrz0[5] * HH(g5);
        bE0 += wih0[4] * HH(g4);  bO0 += wih0[5] * HH(g5);
        aE1 += wrz1[4] * HH(g4);  aO1 += wrz1[5] * HH(g5);
        bE1 += wih1[4] * HH(g4);  bO1 += wih1[5] * HH(g5);
        oE  += woo[4]  * HH(g4);  oO  += woo[5]  * HH(g5);
        aE0 += wrz0[6] * HH(g6);  aO0 += wrz0[7] * HH(g7);
        bE0 += wih0[6] * HH(g6);  bO0 += wih0[7] * HH(g7);
        aE1 += wrz1[6] * HH(g6);  aO1 += wrz1[7] * HH(g7);
        bE1 += wih1[6] * HH(g6);  bO1 += wih1[7] * HH(g7);
        oE  += woo[6]  * HH(g6);  oO  += woo[7]  * HH(g7);
        aE0 += wrz0[8] * HH(h8g); aO0 += wrz0[9] * HH(h9g);
        bE0 += wih0[8] * HH(h8g); bO0 += wih0[9] * HH(h9g);
        aE1 += wrz1[8] * HH(h8g); aO1 += wrz1[9] * HH(h9g);
        bE1 += wih1[8] * HH(h8g); bO1 += wih1[9] * HH(h9g);
        oE  += woo[8]  * HH(h8g); oO  += woo[9]  * HH(h9g);

        v2f arz0 = aE0 + aO0;   // {r_acc, z_acc} for f0
        v2f aih0 = bE0 + bO0;   // {i_acc, h_acc}
        v2f arz1 = aE1 + aO1;
        v2f aih1 = bE1 + bO1;
        v2f ao   = oE + oO;     // {o_f0, o_f1} = o_{t-1}

        hx = tail(arz0.x, arz0.y, aih0.x, aih0.y, hx);
        hy = tail(arz1.x, arz1.y, aih1.x, aih1.y, hy);   // zero-wt lanes stay 0

        pb0[0] = ao.x;                    // f0 always valid (all 64 lanes)
        if (ok1) pb1[0] = ao.y;
        pb0 -= HID; pb1 -= HID;
    }

    // ---- epilogue: o_511 = l1(h_512) at position 0 ----
    {
        float h8g = dsw<0x0011>(hy), h9g = dsw<0x0051>(hy);
        float g0 = hx,          g1 = frot<2>(hx),  g2 = frot<4>(hx),
              g3 = frot<6>(hx), g4 = frot<8>(hx),  g5 = frot<10>(hx),
              g6 = frot<12>(hx), g7 = frot<14>(hx);
        v2f oE = woo[0] * HH(g0) + Boo;  v2f oO = woo[1] * HH(g1);
        oE += woo[2] * HH(g2);  oO += woo[3] * HH(g3);
        oE += woo[4] * HH(g4);  oO += woo[5] * HH(g5);
        oE += woo[6] * HH(g6);  oO += woo[7] * HH(g7);
        oE += woo[8] * HH(h8g); oO += woo[9] * HH(h9g);
        v2f ao = oE + oO;
        pb0[0] = ao.x;
        if (ok1) pb1[0] = ao.y;
    }
    #undef HH
}

extern "C" void kernel_launch(void* const* d_in, const int* in_sizes, int n_in,
                              void* d_out, int out_size, void* d_ws, size_t ws_size,
                              hipStream_t stream) {
    (void)in_sizes; (void)n_in; (void)d_ws; (void)ws_size; (void)out_size;
    dim3 grid(1024), block(64);   // 8 lanes/batch, 8 batches/wave, 1 wave/SIMD
    gru_decoder_kernel<<<grid, block, 0, stream>>>(
        (const float*)d_in[0], (const float*)d_in[1], (const float*)d_in[2],
        (const float*)d_in[3], (const float*)d_in[4], (const float*)d_in[5],
        (const float*)d_in[6], (const float*)d_in[7], (const float*)d_in[8],
        (float*)d_out);
}

// Round 13
// 292.232 us; speedup vs baseline: 1.1839x; 1.1839x over previous
//
#include <hip/hip_runtime.h>

#define HID 10
#define STEPS 512

typedef __attribute__((ext_vector_type(2))) float v2f;
typedef __attribute__((ext_vector_type(4))) float v4f;

// broadcast lane ((lane&0x10)|F) within each 32-lane half -> all lanes of each 16-group
// (one-time use: t=0 peel + epilogue)
template<int F>
static __device__ __forceinline__ float swz(float v) {
    return __int_as_float(__builtin_amdgcn_ds_swizzle(__float_as_int(v), (F << 5) | 0x10));
}

// Lane-parallel fused GRU decoder, 1 feature per lane, 4 batches per wave.
//   batch = blockIdx*4 + (lane>>4); f = lane&15 (f>=10: zero-padded, stores masked)
// v13 = v7 (measured best, 154us) + register-residency fix.
//   Audit: v7 static loop body ~56 instr (~112 cyc/wave-step) but measured
//   issue = 217 cyc/wave-step (VALUBusy 59% x 723 / 2 waves): ~100 instr/step
//   of spill/remat traffic. v7 needs ~90 live VGPR (25 v2f tables + biases +
//   gather + state) but was allocated 64. Fixes:
//   (a) amdgpu_waves_per_eu(2,2): pins 2-wave target -> 256-VGPR budget
//       (R3 proved the attribute moves allocation);
//   (b) tables as NAMED v2f variables (SSA values, no array lowering).
//   Stagger deleted (R7/R10: null). Everything else identical to v7.
__attribute__((amdgpu_waves_per_eu(2, 2)))
__global__ __launch_bounds__(64) void gru_decoder_kernel(
    const float* __restrict__ hidden, const float* __restrict__ w_ih,
    const float* __restrict__ w_hh, const float* __restrict__ b_ih,
    const float* __restrict__ b_hh, const float* __restrict__ l1_w,
    const float* __restrict__ l1_b, const float* __restrict__ l2_w,
    const float* __restrict__ l2_b, float* __restrict__ out)
{
    __shared__ float sWx[640];   // l2_w @ l1_w (64x10)
    __shared__ float sbx[64];    // l2_w @ l1_b + l2_b
    __shared__ float sWgi[300];  // w_ih @ Wx (30x10)
    __shared__ float sbgi[30];   // b_ih + w_ih @ bx
    __shared__ float sWhh[300];  // w_hh copy (t=0 peel + weight build)
    __shared__ float sH[64];     // 4 groups x 16-float rows (gather staging)

    const int lane = threadIdx.x;
    const int f    = lane & 15;
    const int g    = lane >> 4;
    const int b    = blockIdx.x * 4 + g;
    const bool ok  = (f < HID);
    const int fi   = ok ? f : 0;          // clamped index for safe reads

    // ---- preamble: fused weights (fp32, cooperative) ----
    for (int e = lane; e < 640; e += 64) {
        int i = e / 10, j = e - i * 10;
        float acc = 0.f;
        #pragma unroll
        for (int k = 0; k < 10; ++k) acc += l2_w[i * 10 + k] * l1_w[k * 10 + j];
        sWx[e] = acc;
    }
    {
        float acc = l2_b[lane];
        #pragma unroll
        for (int k = 0; k < 10; ++k) acc += l2_w[lane * 10 + k] * l1_b[k];
        sbx[lane] = acc;
    }
    for (int e = lane; e < 300; e += 64) sWhh[e] = w_hh[e];
    __syncthreads();
    for (int e = lane; e < 300; e += 64) {
        int m = e / 10, j = e - m * 10;
        float acc = 0.f;
        for (int k = 0; k < 64; ++k) acc += w_ih[m * 64 + k] * sWx[k * 10 + j];
        sWgi[e] = acc;
    }
    if (lane < 30) {
        float acc = b_ih[lane];
        for (int k = 0; k < 64; ++k) acc += w_ih[lane * 64 + k] * sbx[k];
        sbgi[lane] = acc;
    }
    __syncthreads();

    const float LOG2E = 1.4426950408889634f;
    const float S2    = 2.f * LOG2E;

    // ---- per-lane weights (feature fi), packed across k, NAMED values ----
    #define MKW(k2)                                                              \
        const int k0_##k2 = 2 * (k2), k1_##k2 = 2 * (k2) + 1;                    \
        const v2f wr##k2 = ok ? v2f{                                             \
            -(sWgi[fi * 10 + k0_##k2] + sWhh[fi * 10 + k0_##k2]) * LOG2E,        \
            -(sWgi[fi * 10 + k1_##k2] + sWhh[fi * 10 + k1_##k2]) * LOG2E}        \
            : v2f{0.f, 0.f};                                                     \
        const v2f wz##k2 = ok ? v2f{                                             \
            -(sWgi[(10 + fi) * 10 + k0_##k2] + sWhh[(10 + fi) * 10 + k0_##k2]) * LOG2E, \
            -(sWgi[(10 + fi) * 10 + k1_##k2] + sWhh[(10 + fi) * 10 + k1_##k2]) * LOG2E} \
            : v2f{0.f, 0.f};                                                     \
        const v2f wi##k2 = ok ? v2f{                                             \
            sWgi[(20 + fi) * 10 + k0_##k2] * S2,                                 \
            sWgi[(20 + fi) * 10 + k1_##k2] * S2} : v2f{0.f, 0.f};                \
        const v2f wh##k2 = ok ? v2f{                                             \
            sWhh[(20 + fi) * 10 + k0_##k2] * S2,                                 \
            sWhh[(20 + fi) * 10 + k1_##k2] * S2} : v2f{0.f, 0.f};                \
        const v2f wo##k2 = ok ? v2f{                                             \
            l1_w[fi * 10 + k0_##k2], l1_w[fi * 10 + k1_##k2]} : v2f{0.f, 0.f};
    MKW(0) MKW(1) MKW(2) MKW(3) MKW(4)
    #undef MKW

    const float br = ok ? -(sbgi[fi] + b_hh[fi]) * LOG2E : 0.f;
    const float bz = ok ? -(sbgi[10 + fi] + b_hh[10 + fi]) * LOG2E : 0.f;
    const float bi = ok ? sbgi[20 + fi] * S2 : 0.f;
    const float bh = ok ? b_hh[20 + fi] * S2 : 0.f;
    const float bo = ok ? l1_b[fi] : 0.f;
    const v2f BR2 = {br, 0.f}, BZ2 = {bz, 0.f}, BI2 = {bi, 0.f},
              BH2 = {bh, 0.f}, BO2 = {bo, 0.f};
    // t=0 peel biases (gi = b_ih only)
    const float br0_ = ok ? -(b_ih[fi] + b_hh[fi]) * LOG2E : 0.f;
    const float bz0_ = ok ? -(b_ih[10 + fi] + b_hh[10 + fi]) * LOG2E : 0.f;
    const float bni0 = ok ? b_ih[20 + fi] * S2 : 0.f;

    // ---- initial h (one feature per lane; f>=10 stays exactly 0) ----
    float h = ok ? hidden[(size_t)b * HID + f] : 0.f;

    float* pb = out + (size_t)b * (STEPS * HID) + (size_t)(STEPS - 1) * HID + f;
    float* sHrow = &sH[g * 16];

    // ---- t = 0 peeled: gi = b_ih only (x_0 = 0); raw w_hh dots from LDS ----
    // Produces h1. o_0 = l1(h1) is stored by the first loop iteration.
    {
        float ha[10];
        ha[0] = swz<0>(h); ha[1] = swz<1>(h); ha[2] = swz<2>(h);
        ha[3] = swz<3>(h); ha[4] = swz<4>(h); ha[5] = swz<5>(h);
        ha[6] = swz<6>(h); ha[7] = swz<7>(h); ha[8] = swz<8>(h);
        ha[9] = swz<9>(h);
        float pr = 0.f, pz = 0.f, ph = 0.f;
        #pragma unroll
        for (int k = 0; k < 10; ++k) {
            pr += sWhh[fi * 10 + k] * ha[k];
            pz += sWhh[(10 + fi) * 10 + k] * ha[k];
            ph += sWhh[(20 + fi) * 10 + k] * ha[k];
        }
        float vr = br0_ - pr * LOG2E;
        float vz = bz0_ - pz * LOG2E;
        float r = __builtin_amdgcn_rcpf(1.f + __builtin_amdgcn_exp2f(vr));
        float z = __builtin_amdgcn_rcpf(1.f + __builtin_amdgcn_exp2f(vz));
        float y = bni0 + r * (ph * S2 + bh);
        float n = 1.f - 2.f * __builtin_amdgcn_rcpf(1.f + __builtin_amdgcn_exp2f(y));
        h = ok ? (n + z * (h - n)) : 0.f;
    }

    // ---- t = 1 .. 511 : LDS write+broadcast-read gather, 5-deep pk chains ----
    #pragma unroll 1
    for (int t = 1; t < STEPS; ++t) {
        // stage h: all 64 lanes write (rows padded to 16; f>=10 slots unread)
        sHrow[f] = h;
        __builtin_amdgcn_wave_barrier();      // keep write->reads ordered
        __builtin_amdgcn_sched_barrier(0);
        v4f q0 = *(const v4f*)(sHrow);        // h[0..3]  (broadcast read)
        v4f q1 = *(const v4f*)(sHrow + 4);    // h[4..7]
        v2f q2 = *(const v2f*)(sHrow + 8);    // h[8..9]

        v2f h2_0 = __builtin_shufflevector(q0, q0, 0, 1);
        v2f h2_1 = __builtin_shufflevector(q0, q0, 2, 3);
        v2f h2_2 = __builtin_shufflevector(q1, q1, 0, 1);
        v2f h2_3 = __builtin_shufflevector(q1, q1, 2, 3);
        v2f h2_4 = q2;

        // fma-init into bias consts (no accumulator movs)
        v2f ar = wr0 * h2_0 + BR2;
        v2f az = wz0 * h2_0 + BZ2;
        v2f ai = wi0 * h2_0 + BI2;
        v2f ah = wh0 * h2_0 + BH2;
        v2f ao = wo0 * h2_0 + BO2;
        ar += wr1 * h2_1; az += wz1 * h2_1; ai += wi1 * h2_1;
        ah += wh1 * h2_1; ao += wo1 * h2_1;
        ar += wr2 * h2_2; az += wz2 * h2_2; ai += wi2 * h2_2;
        ah += wh2 * h2_2; ao += wo2 * h2_2;
        ar += wr3 * h2_3; az += wz3 * h2_3; ai += wi3 * h2_3;
        ah += wh3 * h2_3; ao += wo3 * h2_3;
        ar += wr4 * h2_4; az += wz4 * h2_4; ai += wi4 * h2_4;
        ah += wh4 * h2_4; ao += wo4 * h2_4;

        float arx = ar.x + ar.y;
        float azx = az.x + az.y;
        float aix = ai.x + ai.y;
        float ahx = ah.x + ah.y;
        float o   = ao.x + ao.y;          // = l1(h_t) = o_{t-1}

        // r-gate, then fused z/n update with a single rcp:
        //   h' = (ez*(en-1) + h*(en+1)) / ((en+1)*(1+ez))
        float er = __builtin_amdgcn_exp2f(arx);
        float r  = __builtin_amdgcn_rcpf(1.f + er);
        float ez = __builtin_amdgcn_exp2f(azx);
        float y  = __builtin_fmaf(r, ahx, aix);
        float en = __builtin_amdgcn_exp2f(y);
        float p  = en * ez;
        float tt = h - ez;
        float u  = p + tt;
        float num = __builtin_fmaf(h, en, u);          // ez*en - ez + h*en + h
        float v   = en + ez;
        float den = (p + v) + 1.f;                     // (en+1)*(1+ez)
        h = num * __builtin_amdgcn_rcpf(den);          // padded lanes: h stays 0

        if (ok) pb[0] = o;                 // store o_{t-1} (position STEPS-t)
        pb -= HID;
    }

    // ---- epilogue: o_511 = l1(h_512) at position 0 ----
    {
        v2f h2_0 = {swz<0>(h), swz<1>(h)};
        v2f h2_1 = {swz<2>(h), swz<3>(h)};
        v2f h2_2 = {swz<4>(h), swz<5>(h)};
        v2f h2_3 = {swz<6>(h), swz<7>(h)};
        v2f h2_4 = {swz<8>(h), swz<9>(h)};
        v2f ao = wo0 * h2_0 + BO2;
        ao += wo1 * h2_1;
        ao += wo2 * h2_2;
        ao += wo3 * h2_3;
        ao += wo4 * h2_4;
        if (ok) pb[0] = ao.x + ao.y;
    }
}

extern "C" void kernel_launch(void* const* d_in, const int* in_sizes, int n_in,
                              void* d_out, int out_size, void* d_ws, size_t ws_size,
                              hipStream_t stream) {
    (void)in_sizes; (void)n_in; (void)d_ws; (void)ws_size; (void)out_size;
    dim3 grid(2048), block(64);   // 4 batches/wave, 2048 waves -> 2 waves per SIMD
    gru_decoder_kernel<<<grid, block, 0, stream>>>(
        (const float*)d_in[0], (const float*)d_in[1], (const float*)d_in[2],
        (const float*)d_in[3], (const float*)d_in[4], (const float*)d_in[5],
        (const float*)d_in[6], (const float*)d_in[7], (const float*)d_in[8],
        (float*)d_out);
}